// Round 7
// baseline (245.979 us; speedup 1.0000x reference)
//
#include <hip/hip_runtime.h>
#include <stdint.h>

typedef unsigned short u16;
typedef float v4f __attribute__((ext_vector_type(4)));
typedef short v8s __attribute__((ext_vector_type(8)));

#define B_   8192
#define IN_  1024
#define OUT_ 1024
#define D_   8

#define BM 128
#define BN 128
#define BK 64             // K-tile per phase: 32 MFMAs, 1 barrier

__device__ __forceinline__ u16 f2bf(float f) {
  uint32_t u = __float_as_uint(f);
  u += 0x7fffu + ((u >> 16) & 1u);   // RTNE (inputs finite)
  return (u16)(u >> 16);
}

// ---- prep: input + weights f32 -> bf16 (proven) ----------------------------
__global__ __launch_bounds__(256) void convert_both(
    const float* __restrict__ input, const float* __restrict__ weights,
    u16* __restrict__ inBf, u16* __restrict__ wtBf) {
  int i4 = blockIdx.x * blockDim.x + threadIdx.x;
  const int n4 = (B_ * IN_) / 4;
  const float* src;
  u16* dst;
  int idx;
  if (i4 < n4) { src = input;   dst = inBf; idx = i4; }
  else         { src = weights; dst = wtBf; idx = i4 - n4; }
  float4 v = ((const float4*)src)[idx];
  ushort4 o;
  o.x = f2bf(v.x); o.y = f2bf(v.y); o.z = f2bf(v.z); o.w = f2bf(v.w);
  ((ushort4*)dst)[idx] = o;
}

__device__ __forceinline__ void gload_lds16(const u16* g, u16* l) {
  typedef __attribute__((address_space(1))) void gvoid;
  typedef __attribute__((address_space(3))) void lvoid;
  __builtin_amdgcn_global_load_lds((gvoid*)g, (lvoid*)l, 16, 0, 0);
}

// ---- GEMM: telescoping rescale (R6-proven) + STATIC buffer addressing ------
// R6 counter post-mortem: VALUBusy 30% with zero staging VALU => per-tile
// address recompute caused by runtime buffer-pointer rotation. Fix: linearize
// t = dd*16+it (0..127), peel t=0,1, unroll groups of 6 (= lcm(2,3)); buffer
// indices are then compile-time constants:
//   A compute buf = t&1, Bc = t%3, B stage buf = (t+2)%3
// so every ds_read is hoisted-base + offset: imm, and gload_lds LDS dests are
// static. Schedule, vmcnt ledger, rescale math identical to R6:
//   per tile: issue A(t+1)[4], B(t+2)[4]; compute; s_waitcnt vmcnt(4); barrier
//   t==126: vmcnt(0); t==127: no wait/barrier.
//   rescale interlude when t%16==0 (t>0): acc *= g(w[:,dd-1])/g(w[:,dd]).
__global__ __launch_bounds__(256, 2) void gemm_rs(
    const u16* __restrict__ A,        // [B_][IN_] bf16 input (unscaled)
    const u16* __restrict__ Wt,       // [D_][OUT_][IN_] bf16
    const float* __restrict__ w,      // [B_][D_]
    const float* __restrict__ biases, // [D_][OUT_]
    float* __restrict__ out) {        // [B_][OUT_]
  __shared__ __align__(16) u16 As[2][BM * BK];   // 32 KB
  __shared__ __align__(16) u16 Bs[3][BN * BK];   // 48 KB -> 80 KB: 2 blk/CU

  // R0-proven mapping: all 8 blocks sharing an A-panel are co-XCD.
  const int id   = blockIdx.x;                // 512 blocks
  const int xcd  = id & 7;
  const int slot = id >> 3;
  const int by   = xcd + ((slot & 7) << 3);   // 0..63
  const int bx   = slot >> 3;                 // 0..7

  const int tid  = threadIdx.x;
  const int wid  = tid >> 6;
  const int lane = tid & 63;
  const int wr   = wid >> 1, wc = wid & 1;
  const int quad = lane >> 4, l16 = lane & 15;
  const int m0   = by * BM;
  const int n0   = bx * BN;

  // staging geometry (proven): chunk c = wid*256+j*64+lane; row = c>>3;
  // LDS chunk (lane&7) holds global chunk swz = (lane&7)^((lane>>3)&7).
  const int swz  = (lane & 7) ^ ((lane >> 3) & 7);
  const int rowS = wid * 32 + (lane >> 3);    // + j*8
  const u16* aBase[4];
  const u16* bBase[4];
  int cOff[4];
#pragma unroll
  for (int j = 0; j < 4; ++j) {
    const int row = rowS + j * 8;
    aBase[j] = A  + (size_t)(m0 + row) * IN_ + swz * 8;
    bBase[j] = Wt + (size_t)(n0 + row) * IN_ + swz * 8;
    cOff[j]  = (wid * 256 + j * 64 + lane) * 8;
  }

  // fragment LDS offsets (u16 index), de-swizzled
  const int aRow = wr * 64 + l16;
  const int bRow = wc * 64 + l16;
  const int e    = l16 & 7;
  int aCol[2];
#pragma unroll
  for (int h = 0; h < 2; ++h) aCol[h] = ((quad + 4 * h) ^ e) * 8;

  const v4f vzero = {0.f, 0.f, 0.f, 0.f};
  v4f acc[4][4];
#pragma unroll
  for (int mt = 0; mt < 4; ++mt)
#pragma unroll
    for (int nt = 0; nt < 4; ++nt) acc[mt][nt] = vzero;

  // wp[mt][r] = g(w[row, current plane]); init plane 0
  float wp[4][4];
#pragma unroll
  for (int mt = 0; mt < 4; ++mt)
#pragma unroll
    for (int r = 0; r < 4; ++r) {
      const int grow = m0 + wr * 64 + mt * 16 + quad * 4 + r;
      wp[mt][r] = fmaxf(w[(size_t)grow * D_], 1e-30f);
    }

// -- plane-boundary rescale: acc *= g(w[:,dd-1]) / g(w[:,dd]) (7 occurrences)
#define RESCALE(ddv)                                                    \
  {                                                                     \
    _Pragma("unroll") for (int mt = 0; mt < 4; ++mt) {                  \
      _Pragma("unroll") for (int r = 0; r < 4; ++r) {                   \
        const int grow = m0 + wr * 64 + mt * 16 + quad * 4 + r;         \
        const float wn = fmaxf(w[(size_t)grow * D_ + (ddv)], 1e-30f);   \
        const float ratio = wp[mt][r] / wn;                             \
        wp[mt][r] = wn;                                                 \
        _Pragma("unroll") for (int nt = 0; nt < 4; ++nt)                \
          acc[mt][nt][r] *= ratio;                                      \
      }                                                                 \
    }                                                                   \
  }

// -- one K-tile; kA/kBc/kBs are COMPILE-TIME buffer indices, t is uniform ----
#define TILE_BODY(kA, kBc, kBs, t)                                      \
  {                                                                     \
    const int t_ = (t);                                                 \
    if (t_ && !(t_ & 15)) RESCALE(t_ >> 4);                             \
    if (t_ < 127) {          /* stage A(t+1), slice wraps mod 16 */     \
      const int sit = (t_ + 1) & 15;                                    \
      _Pragma("unroll") for (int j = 0; j < 4; ++j)                     \
        gload_lds16(aBase[j] + sit * BK, &As[(kA) ^ 1][cOff[j]]);       \
    }                                                                   \
    if (t_ < 126) {          /* stage B(t+2) */                         \
      const int su = t_ + 2;                                            \
      const size_t bo = (size_t)(su >> 4) * (OUT_ * IN_) +              \
                        (size_t)(su & 15) * BK;                         \
      _Pragma("unroll") for (int j = 0; j < 4; ++j)                     \
        gload_lds16(bBase[j] + bo, &Bs[kBs][cOff[j]]);                  \
    }                                                                   \
    __builtin_amdgcn_s_setprio(1);                                      \
    _Pragma("unroll") for (int h = 0; h < 2; ++h) {                     \
      v8s af[4], bf[4];                                                 \
      _Pragma("unroll") for (int mt = 0; mt < 4; ++mt)                  \
        af[mt] = *(const v8s*)(&As[kA][(aRow + mt * 16) * BK + aCol[h]]); \
      _Pragma("unroll") for (int nt = 0; nt < 4; ++nt)                  \
        bf[nt] = *(const v8s*)(&Bs[kBc][(bRow + nt * 16) * BK + aCol[h]]); \
      _Pragma("unroll") for (int mt = 0; mt < 4; ++mt)                  \
        _Pragma("unroll") for (int nt = 0; nt < 4; ++nt)                \
          acc[mt][nt] = __builtin_amdgcn_mfma_f32_16x16x32_bf16(        \
              af[mt], bf[nt], acc[mt][nt], 0, 0, 0);                    \
    }                                                                   \
    __builtin_amdgcn_s_setprio(0);                                      \
    if (t_ < 126) {                                                     \
      asm volatile("s_waitcnt vmcnt(4)" ::: "memory");                  \
      __builtin_amdgcn_s_barrier();                                     \
    } else if (t_ == 126) {                                             \
      asm volatile("s_waitcnt vmcnt(0)" ::: "memory");                  \
      __builtin_amdgcn_s_barrier();                                     \
    }                                                                   \
  }

  // ---- prologue: A(0) -> As[0], B(0) -> Bs[0], B(1) -> Bs[1]
#pragma unroll
  for (int j = 0; j < 4; ++j) gload_lds16(aBase[j], &As[0][cOff[j]]);
#pragma unroll
  for (int j = 0; j < 4; ++j) gload_lds16(bBase[j], &Bs[0][cOff[j]]);
#pragma unroll
  for (int j = 0; j < 4; ++j)
    gload_lds16(bBase[j] + (size_t)BK, &Bs[1][cOff[j]]);   // (dd0, it1)
  asm volatile("s_waitcnt vmcnt(4) lgkmcnt(0)" ::: "memory"); // A0+B0 done
  __builtin_amdgcn_s_barrier();

  // ---- t=0,1 peeled; then 21 groups of 6 (t = 2+6g .. 7+6g)
  //   A buf = t&1; B compute = t%3; B stage = (t+2)%3  (t0 = 2+6g: even, %3==2)
  TILE_BODY(0, 0, 2, 0);
  TILE_BODY(1, 1, 0, 1);
  for (int g = 0; g < 21; ++g) {
    const int t0 = 2 + 6 * g;
    TILE_BODY(0, 2, 1, t0 + 0);
    TILE_BODY(1, 0, 2, t0 + 1);
    TILE_BODY(0, 1, 0, t0 + 2);
    TILE_BODY(1, 2, 1, t0 + 3);
    TILE_BODY(0, 0, 2, t0 + 4);
    TILE_BODY(1, 1, 0, t0 + 5);
  }

  // ---- epilogue: out = acc * g(w[:,7]) + sum_d w[b,d]*biases[d,o]
  float bcol[4][8];
#pragma unroll
  for (int nt = 0; nt < 4; ++nt) {
    const int col = n0 + wc * 64 + nt * 16 + l16;
#pragma unroll
    for (int dd = 0; dd < 8; ++dd) bcol[nt][dd] = biases[dd * OUT_ + col];
  }
#pragma unroll
  for (int mt = 0; mt < 4; ++mt) {
#pragma unroll
    for (int r = 0; r < 4; ++r) {
      const int grow = m0 + wr * 64 + mt * 16 + quad * 4 + r;
      const v4f* wpg = (const v4f*)(w + (size_t)grow * D_);
      const v4f wa = wpg[0], wb = wpg[1];
      const float wlast = wp[mt][r];
#pragma unroll
      for (int nt = 0; nt < 4; ++nt) {
        const int col = n0 + wc * 64 + nt * 16 + l16;
        const float bias = wa[0] * bcol[nt][0] + wa[1] * bcol[nt][1] +
                           wa[2] * bcol[nt][2] + wa[3] * bcol[nt][3] +
                           wb[0] * bcol[nt][4] + wb[1] * bcol[nt][5] +
                           wb[2] * bcol[nt][6] + wb[3] * bcol[nt][7];
        out[(size_t)grow * OUT_ + col] = acc[mt][nt][r] * wlast + bias;
      }
    }
  }
}

extern "C" void kernel_launch(void* const* d_in, const int* in_sizes, int n_in,
                              void* d_out, int out_size, void* d_ws, size_t ws_size,
                              hipStream_t stream) {
  const float* input   = (const float*)d_in[0];
  const float* w       = (const float*)d_in[1];
  const float* weights = (const float*)d_in[2];
  const float* biases  = (const float*)d_in[3];
  float* out = (float*)d_out;

  u16* inBf = (u16*)d_ws;                               // 16 MB
  u16* wtBf = inBf + (size_t)B_ * IN_;                  // 16 MB

  const int totalF4 = (B_ * IN_ + D_ * OUT_ * IN_) / 4;
  convert_both<<<dim3(totalF4 / 256), 256, 0, stream>>>(input, weights, inBf, wtBf);
  gemm_rs<<<dim3(512), 256, 0, stream>>>(inBf, wtBf, w, biases, out);
}

// Round 8
// 245.036 us; speedup vs baseline: 1.0038x; 1.0038x over previous
//
#include <hip/hip_runtime.h>
#include <stdint.h>

typedef unsigned short u16;
typedef float v4f __attribute__((ext_vector_type(4)));
typedef short v8s __attribute__((ext_vector_type(8)));

#define B_   8192
#define IN_  1024
#define OUT_ 1024
#define D_   8

#define BM 128
#define BN 128
#define BK 64                      // K-tile: 32 MFMAs, 1 barrier
#define MBLK_STRIDE (128 * 128 * 8)   // u16 per m-block of Ablk

__device__ __forceinline__ u16 f2bf(float f) {
  uint32_t u = __float_as_uint(f);
  u += 0x7fffu + ((u >> 16) & 1u);   // RTNE (inputs finite)
  return (u16)(u >> 16);
}

// ---- prep (fused): input -> BLOCKED bf16 Ablk[64][128kc][128row][8],
//                    weights -> flat bf16.
// Blocked A layout lets the GEMM load MFMA A-fragments directly global->VGPR
// with perfect coalescing (16 lanes x consecutive rows x 16B), removing A
// from LDS entirely (R7 post-mortem: LDS BW is the structural cap).
__global__ __launch_bounds__(256) void convert_fused(
    const float* __restrict__ input, const float* __restrict__ weights,
    u16* __restrict__ Ablk, u16* __restrict__ wtBf) {
  const int bid = blockIdx.x;
  const int t   = threadIdx.x;
  if (bid < 1024) {
    // input block: mb (128 rows) x kt (64 cols) tile, LDS transpose
    __shared__ u16 T[128][66];     // +2 u16 pad -> 33-dword row stride (odd)
    const int mb = bid >> 4;       // 0..63
    const int kt = bid & 15;       // 0..15
    const float4* in4 = (const float4*)input;
#pragma unroll
    for (int j = 0; j < 8; ++j) {  // read coalesced: 16 float4 per row
      const int f   = j * 256 + t;
      const int row = f >> 4;
      const int c4  = f & 15;
      float4 v = in4[(size_t)(mb * 128 + row) * (IN_ / 4) + kt * 16 + c4];
      T[row][c4 * 4 + 0] = f2bf(v.x);
      T[row][c4 * 4 + 1] = f2bf(v.y);
      T[row][c4 * 4 + 2] = f2bf(v.z);
      T[row][c4 * 4 + 3] = f2bf(v.w);
    }
    __syncthreads();
#pragma unroll
    for (int j = 0; j < 4; ++j) {  // write blocked: [kc][row][8], coalesced
      const int c   = j * 256 + t;
      const int kc  = c >> 7;      // 0..7
      const int row = c & 127;
      const uint32_t* tp = (const uint32_t*)&T[row][kc * 8];
      uint4 o = {tp[0], tp[1], tp[2], tp[3]};
      u16* dp = Ablk + (size_t)mb * MBLK_STRIDE +
                (size_t)(kt * 8 + kc) * 1024 + row * 8;
      *(uint4*)dp = o;
    }
  } else {
    // weights: flat f32 -> bf16 (2M float4 over 8192 blocks)
    const int i4 = (bid - 1024) * 256 + t;
    float4 v = ((const float4*)weights)[i4];
    ushort4 o;
    o.x = f2bf(v.x); o.y = f2bf(v.y); o.z = f2bf(v.z); o.w = f2bf(v.w);
    ((ushort4*)wtBf)[i4] = o;
  }
}

__device__ __forceinline__ void gload_lds16(const u16* g, u16* l) {
  typedef __attribute__((address_space(1))) void gvoid;
  typedef __attribute__((address_space(3))) void lvoid;
  __builtin_amdgcn_global_load_lds((gvoid*)g, (lvoid*)l, 16, 0, 0);
}

// ---- GEMM: R6 schedule (telescoping rescale, counted vmcnt, B tribuf) with
// A-fragments loaded DIRECTLY global->VGPR from the blocked layout.
// R6 post-mortem arithmetic: per CU-tile MFMA=1242cyc but LDS=~2048cyc (reads
// 1536 + staging writes 512) -> LDS-BW-bound at 43.5% MfmaUtil. Removing A
// from LDS cuts LDS to ~1024cyc < MFMA -> MFMA-bound. Per-lane A values are
// bit-identical to R6's LDS-read fragments (row=wr*64+mt*16+l16,
// kchunk=it*8+quad+4h), so correctness transfers 1:1.
// vmcnt ledger: per tile issue Afr(t+1)[8] then B(t+2)[4]; at end-of-tile the
// queue is [B(t+1)4, Afr(t+1)8, B(t+2)4] -> vmcnt(4) (need B(t+1)+Afr(t+1)).
// t==126: vmcnt(0). t==127: nothing. Prologue: [Afr0 8, B0 4, B1 4]->vmcnt(4).
// A-frag banks are ping-pong registers; it-loop unrolled x2 ONLY (small body,
// R7 lesson: big unrolls regress) -> bank index static (rule #20).
__global__ __launch_bounds__(256, 2) void gemm_af(
    const u16* __restrict__ Ablk,     // blocked bf16 input
    const u16* __restrict__ Wt,       // [D_][OUT_][IN_] bf16
    const float* __restrict__ w,      // [B_][D_]
    const float* __restrict__ biases, // [D_][OUT_]
    float* __restrict__ out) {        // [B_][OUT_]
  __shared__ __align__(16) u16 Bs[3][BN * BK];   // 48 KB only -> 2 blk/CU

  const int id   = blockIdx.x;                // 512 blocks
  const int xcd  = id & 7;
  const int slot = id >> 3;
  const int by   = xcd + ((slot & 7) << 3);   // 0..63 (co-XCD A-panel sharing)
  const int bx   = slot >> 3;                 // 0..7

  const int tid  = threadIdx.x;
  const int wid  = tid >> 6;
  const int lane = tid & 63;
  const int wr   = wid >> 1, wc = wid & 1;
  const int quad = lane >> 4, l16 = lane & 15;
  const int m0   = by * BM;
  const int n0   = bx * BN;

  // ---- B staging geometry (R6-proven, XOR swizzle)
  const int swz  = (lane & 7) ^ ((lane >> 3) & 7);
  const int rowS = wid * 32 + (lane >> 3);
  const u16* bBase[4];
  int cOff[4];
#pragma unroll
  for (int j = 0; j < 4; ++j) {
    bBase[j] = Wt + (size_t)(n0 + rowS + j * 8) * IN_ + swz * 8;
    cOff[j]  = (wid * 256 + j * 64 + lane) * 8;
  }

  // ---- B fragment LDS offsets (de-swizzled)
  const int bRow = wc * 64 + l16;
  const int e    = l16 & 7;
  int bCol[2];
#pragma unroll
  for (int h = 0; h < 2; ++h) bCol[h] = ((quad + 4 * h) ^ e) * 8;

  // ---- A fragment base (blocked layout, per-lane)
  const u16* aF = Ablk + (size_t)by * MBLK_STRIDE +
                  (size_t)((wr * 64 + l16) * 8 + quad * 1024);
  // frag (mt,h) at tile it:  aF + mt*128 + it*8192 + h*4096   (u16 units)

  const v4f vzero = {0.f, 0.f, 0.f, 0.f};
  v4f acc[4][4];
#pragma unroll
  for (int mt = 0; mt < 4; ++mt)
#pragma unroll
    for (int nt = 0; nt < 4; ++nt) acc[mt][nt] = vzero;

  // wp[mt][r] = g(w[row, current plane]); init plane 0
  float wp[4][4];
#pragma unroll
  for (int mt = 0; mt < 4; ++mt)
#pragma unroll
    for (int r = 0; r < 4; ++r) {
      const int grow = m0 + wr * 64 + mt * 16 + quad * 4 + r;
      wp[mt][r] = fmaxf(w[(size_t)grow * D_], 1e-30f);
    }

  v8s fr0[4][2], fr1[4][2];   // ping-pong A-fragment banks

#define LOAD_AFRAGS(BANK, nit_)                                         \
  _Pragma("unroll") for (int mt = 0; mt < 4; ++mt)                      \
    _Pragma("unroll") for (int h = 0; h < 2; ++h)                       \
      BANK[mt][h] =                                                     \
          *(const v8s*)(aF + mt * 128 + (size_t)(nit_)*8192 + h * 4096);

#define RESCALE(ddv)                                                    \
  {                                                                     \
    _Pragma("unroll") for (int mt = 0; mt < 4; ++mt) {                  \
      _Pragma("unroll") for (int r = 0; r < 4; ++r) {                   \
        const int grow = m0 + wr * 64 + mt * 16 + quad * 4 + r;         \
        const float wn = fmaxf(w[(size_t)grow * D_ + (ddv)], 1e-30f);   \
        const float ratio = wp[mt][r] / wn;                             \
        wp[mt][r] = wn;                                                 \
        _Pragma("unroll") for (int nt = 0; nt < 4; ++nt)                \
          acc[mt][nt][r] *= ratio;                                      \
      }                                                                 \
    }                                                                   \
  }

#define TILE(BANKC, BANKN, itv, ddv)                                    \
  {                                                                     \
    const int t_ = (ddv)*16 + (itv);                                    \
    if (t_ < 127) {             /* A-frags for t+1 (it wraps per plane) */ \
      const int nit = ((itv) + 1) & 15;                                 \
      LOAD_AFRAGS(BANKN, nit);                                          \
    }                                                                   \
    if (t_ < 126) {             /* B tile t+2 -> bS */                  \
      const int su = t_ + 2;                                            \
      const size_t bo = (size_t)(su >> 4) * (OUT_ * IN_) +              \
                        (size_t)(su & 15) * BK;                         \
      _Pragma("unroll") for (int j = 0; j < 4; ++j)                     \
        gload_lds16(bBase[j] + bo, bS + cOff[j]);                       \
    }                                                                   \
    __builtin_amdgcn_s_setprio(1);                                      \
    _Pragma("unroll") for (int h = 0; h < 2; ++h) {                     \
      v8s bf[4];                                                        \
      _Pragma("unroll") for (int nt = 0; nt < 4; ++nt)                  \
        bf[nt] = *(const v8s*)(bC + (bRow + nt * 16) * BK + bCol[h]);   \
      _Pragma("unroll") for (int mt = 0; mt < 4; ++mt)                  \
        _Pragma("unroll") for (int nt = 0; nt < 4; ++nt)                \
          acc[mt][nt] = __builtin_amdgcn_mfma_f32_16x16x32_bf16(        \
              BANKC[mt][h], bf[nt], acc[mt][nt], 0, 0, 0);              \
    }                                                                   \
    __builtin_amdgcn_s_setprio(0);                                      \
    if (t_ < 126) {                                                     \
      asm volatile("s_waitcnt vmcnt(4)" ::: "memory");                  \
      __builtin_amdgcn_s_barrier();                                     \
    } else if (t_ == 126) {                                             \
      asm volatile("s_waitcnt vmcnt(0)" ::: "memory");                  \
      __builtin_amdgcn_s_barrier();                                     \
    }                                                                   \
    u16* tb = bC; bC = bN; bN = bS; bS = tb;                            \
  }

  // rotating B buffer pointers
  u16* bC = Bs[0];
  u16* bN = Bs[1];
  u16* bS = Bs[2];

  // ---- prologue: Afr(0) -> fr0; B(0) -> Bs[0]; B(1) -> Bs[1]
  LOAD_AFRAGS(fr0, 0);
#pragma unroll
  for (int j = 0; j < 4; ++j) gload_lds16(bBase[j], &Bs[0][cOff[j]]);
#pragma unroll
  for (int j = 0; j < 4; ++j)
    gload_lds16(bBase[j] + (size_t)BK, &Bs[1][cOff[j]]);   // (dd0, it1)
  asm volatile("s_waitcnt vmcnt(4) lgkmcnt(0)" ::: "memory"); // Afr0+B0 done
  __builtin_amdgcn_s_barrier();

  // ---- main: dd outer (7 rescale interludes), it inner unrolled x2
  for (int dd = 0; dd < D_; ++dd) {
    if (dd > 0) RESCALE(dd);
    for (int itp = 0; itp < 8; ++itp) {
      TILE(fr0, fr1, itp * 2, dd);
      TILE(fr1, fr0, itp * 2 + 1, dd);
    }
  }

  // ---- epilogue: out = acc * g(w[:,7]) + sum_d w[b,d]*biases[d,o]
  float bcol[4][8];
#pragma unroll
  for (int nt = 0; nt < 4; ++nt) {
    const int col = n0 + wc * 64 + nt * 16 + l16;
#pragma unroll
    for (int dd = 0; dd < 8; ++dd) bcol[nt][dd] = biases[dd * OUT_ + col];
  }
#pragma unroll
  for (int mt = 0; mt < 4; ++mt) {
#pragma unroll
    for (int r = 0; r < 4; ++r) {
      const int grow = m0 + wr * 64 + mt * 16 + quad * 4 + r;
      const v4f* wpg = (const v4f*)(w + (size_t)grow * D_);
      const v4f wa = wpg[0], wb = wpg[1];
      const float wlast = wp[mt][r];
#pragma unroll
      for (int nt = 0; nt < 4; ++nt) {
        const int col = n0 + wc * 64 + nt * 16 + l16;
        const float bias = wa[0] * bcol[nt][0] + wa[1] * bcol[nt][1] +
                           wa[2] * bcol[nt][2] + wa[3] * bcol[nt][3] +
                           wb[0] * bcol[nt][4] + wb[1] * bcol[nt][5] +
                           wb[2] * bcol[nt][6] + wb[3] * bcol[nt][7];
        out[(size_t)grow * OUT_ + col] = acc[mt][nt][r] * wlast + bias;
      }
    }
  }
}

extern "C" void kernel_launch(void* const* d_in, const int* in_sizes, int n_in,
                              void* d_out, int out_size, void* d_ws, size_t ws_size,
                              hipStream_t stream) {
  const float* input   = (const float*)d_in[0];
  const float* w       = (const float*)d_in[1];
  const float* weights = (const float*)d_in[2];
  const float* biases  = (const float*)d_in[3];
  float* out = (float*)d_out;

  u16* Ablk = (u16*)d_ws;                               // 16 MB (blocked)
  u16* wtBf = Ablk + (size_t)B_ * IN_;                  // 16 MB

  // 1024 input-blocking blocks + 8192 weight-convert blocks
  convert_fused<<<dim3(1024 + 8192), 256, 0, stream>>>(input, weights, Ablk, wtBf);
  gemm_af<<<dim3(512), 256, 0, stream>>>(Ablk, wtBf, w, biases, out);
}

// Round 9
// 235.000 us; speedup vs baseline: 1.0467x; 1.0427x over previous
//
#include <hip/hip_runtime.h>
#include <stdint.h>

typedef unsigned short u16;
typedef float v4f __attribute__((ext_vector_type(4)));
typedef short v8s __attribute__((ext_vector_type(8)));

#define B_   8192
#define IN_  1024
#define OUT_ 1024
#define D_   8

#define BM 128
#define BN 128
#define BK 64             // K-tile per phase: 32 MFMAs, 1 barrier

__device__ __forceinline__ u16 f2bf(float f) {
  uint32_t u = __float_as_uint(f);
  u += 0x7fffu + ((u >> 16) & 1u);   // RTNE (inputs finite)
  return (u16)(u >> 16);
}

// ---- prep: input + weights f32 -> bf16 (proven) ----------------------------
__global__ __launch_bounds__(256) void convert_both(
    const float* __restrict__ input, const float* __restrict__ weights,
    u16* __restrict__ inBf, u16* __restrict__ wtBf) {
  int i4 = blockIdx.x * blockDim.x + threadIdx.x;
  const int n4 = (B_ * IN_) / 4;
  const float* src;
  u16* dst;
  int idx;
  if (i4 < n4) { src = input;   dst = inBf; idx = i4; }
  else         { src = weights; dst = wtBf; idx = i4 - n4; }
  float4 v = ((const float4*)src)[idx];
  ushort4 o;
  o.x = f2bf(v.x); o.y = f2bf(v.y); o.z = f2bf(v.z); o.w = f2bf(v.w);
  ((ushort4*)dst)[idx] = o;
}

__device__ __forceinline__ void gload_lds16(const u16* g, u16* l) {
  typedef __attribute__((address_space(1))) void gvoid;
  typedef __attribute__((address_space(3))) void lvoid;
  __builtin_amdgcn_global_load_lds((gvoid*)g, (lvoid*)l, 16, 0, 0);
}

// ---- GEMM with telescoping accumulator rescale (R6, empirical best) --------
// out[b,o] = sum_d w[b,d] * (input[b,:] . weights[d,o,:]) + bias-term.
// ONE accumulator bank with invariant "acc is in units of 1/g(w[row,dd_cur])":
//   at plane boundary: acc *= g(w[row,prev]) / g(w[row,next])   (7 interludes)
//   epilogue:          out  = acc * g(w[row,7]) + bias
// g(x)=max(x,1e-30) guards w==0. K-loop is pure gload_lds staging (A 4 + B 4
// per tile, no ds_write/cvt/f32 loads) + counted-vmcnt single-barrier tiles.
// vmcnt ledger (4 loads per issue-group, FIFO):
//   top of t: issue A(t+1) then B(t+2); queue [B(t+1), A(t+1), B(t+2)]
//   end of t: need B(t+1)+A(t+1) -> vmcnt(4).  t==126: vmcnt(0).  t==127: none.
// Session evidence locked in here:
//   R1: second acc bank -> occupancy halved. R2: in-phase reg-staging ->
//   Mfma 28%. R5: ds_write staging poisons per-phase lgkmcnt + 8-phase @
//   128^2/4-wave regresses (= guide m232). R7: full static unroll (code
//   bloat) regresses. R8: A-frags from global move dup reads LDS->L2 (slower
//   pipe) -> regress. This structure = m97-family ceiling (~43% MfmaUtil).
__global__ __launch_bounds__(256, 2) void gemm_rs(
    const u16* __restrict__ A,        // [B_][IN_] bf16 input (unscaled)
    const u16* __restrict__ Wt,       // [D_][OUT_][IN_] bf16
    const float* __restrict__ w,      // [B_][D_]
    const float* __restrict__ biases, // [D_][OUT_]
    float* __restrict__ out) {        // [B_][OUT_]
  __shared__ __align__(16) u16 As[2][BM * BK];   // 32 KB
  __shared__ __align__(16) u16 Bs[3][BN * BK];   // 48 KB -> 80 KB: 2 blk/CU

  // R0-proven mapping: all 8 blocks sharing an A-panel are co-XCD.
  const int id   = blockIdx.x;                // 512 blocks
  const int xcd  = id & 7;
  const int slot = id >> 3;
  const int by   = xcd + ((slot & 7) << 3);   // 0..63
  const int bx   = slot >> 3;                 // 0..7

  const int tid  = threadIdx.x;
  const int wid  = tid >> 6;
  const int lane = tid & 63;
  const int wr   = wid >> 1, wc = wid & 1;
  const int quad = lane >> 4, l16 = lane & 15;
  const int m0   = by * BM;
  const int n0   = bx * BN;

  // staging geometry (proven): chunk c = wid*256+j*64+lane; row = c>>3;
  // LDS chunk (lane&7) holds global chunk swz = (lane&7)^((lane>>3)&7).
  const int swz  = (lane & 7) ^ ((lane >> 3) & 7);
  const int rowS = wid * 32 + (lane >> 3);    // + j*8
  const u16* aBase[4];
  const u16* bBase[4];
  int cOff[4];
#pragma unroll
  for (int j = 0; j < 4; ++j) {
    const int row = rowS + j * 8;
    aBase[j] = A  + (size_t)(m0 + row) * IN_ + swz * 8;
    bBase[j] = Wt + (size_t)(n0 + row) * IN_ + swz * 8;
    cOff[j]  = (wid * 256 + j * 64 + lane) * 8;
  }

  // fragment LDS offsets (u16 index), de-swizzled
  const int aRow = wr * 64 + l16;
  const int bRow = wc * 64 + l16;
  const int e    = l16 & 7;
  int aCol[2];
#pragma unroll
  for (int h = 0; h < 2; ++h) aCol[h] = ((quad + 4 * h) ^ e) * 8;

  const v4f vzero = {0.f, 0.f, 0.f, 0.f};
  v4f acc[4][4];
#pragma unroll
  for (int mt = 0; mt < 4; ++mt)
#pragma unroll
    for (int nt = 0; nt < 4; ++nt) acc[mt][nt] = vzero;

  // wp[mt][r] = g(w[row, current plane]); init plane 0
  float wp[4][4];
#pragma unroll
  for (int mt = 0; mt < 4; ++mt)
#pragma unroll
    for (int r = 0; r < 4; ++r) {
      const int grow = m0 + wr * 64 + mt * 16 + quad * 4 + r;
      wp[mt][r] = fmaxf(w[(size_t)grow * D_], 1e-30f);
    }

  // rotating buffers
  u16* aC_ = As[0];
  u16* aN  = As[1];
  u16* bC  = Bs[0];
  u16* bN  = Bs[1];
  u16* bS  = Bs[2];

  // ---- prologue: A(slice 0) -> aC_, B(t=0) -> bC, B(t=1) -> bN
#pragma unroll
  for (int j = 0; j < 4; ++j) gload_lds16(aBase[j], aC_ + cOff[j]);
#pragma unroll
  for (int j = 0; j < 4; ++j) gload_lds16(bBase[j], bC + cOff[j]);
#pragma unroll
  for (int j = 0; j < 4; ++j)
    gload_lds16(bBase[j] + (size_t)BK, bN + cOff[j]);   // (dd0, it1)
  asm volatile("s_waitcnt vmcnt(4) lgkmcnt(0)" ::: "memory"); // A0+B0 done
  __builtin_amdgcn_s_barrier();

  // ---- main: dd outer (7 cheap rescale interludes), it inner, t = dd*16+it
  for (int dd = 0; dd < D_; ++dd) {
    if (dd > 0) {
      // plane transition: acc *= g(w[:,dd-1]) / g(w[:,dd])
#pragma unroll
      for (int mt = 0; mt < 4; ++mt) {
#pragma unroll
        for (int r = 0; r < 4; ++r) {
          const int grow = m0 + wr * 64 + mt * 16 + quad * 4 + r;
          const float wn = fmaxf(w[(size_t)grow * D_ + dd], 1e-30f);
          const float ratio = wp[mt][r] / wn;
          wp[mt][r] = wn;
#pragma unroll
          for (int nt = 0; nt < 4; ++nt) acc[mt][nt][r] *= ratio;
        }
      }
    }
    for (int it = 0; it < 16; ++it) {
      const int t = dd * 16 + it;

      // -- stage A slice (t+1), 1-ahead (A independent of dd; slice wraps)
      if (t < 127) {
        const int sit = (it + 1) & 15;
#pragma unroll
        for (int j = 0; j < 4; ++j)
          gload_lds16(aBase[j] + sit * BK, aN + cOff[j]);
      }
      // -- stage B tile (t+2), 2-ahead (issued AFTER A: keeps A older in FIFO)
      if (t < 126) {
        const int it2  = it + 2;
        const int sdd2 = dd + (it2 >> 4);
        const int sit2 = it2 & 15;
#pragma unroll
        for (int j = 0; j < 4; ++j)
          gload_lds16(bBase[j] + (size_t)sdd2 * (OUT_ * IN_) + sit2 * BK,
                      bS + cOff[j]);
      }

      // -- compute on aC_, bC
      __builtin_amdgcn_s_setprio(1);
#pragma unroll
      for (int h = 0; h < 2; ++h) {
        v8s af[4], bf[4];
#pragma unroll
        for (int mt = 0; mt < 4; ++mt)
          af[mt] = *(const v8s*)(aC_ + (aRow + mt * 16) * BK + aCol[h]);
#pragma unroll
        for (int nt = 0; nt < 4; ++nt)
          bf[nt] = *(const v8s*)(bC + (bRow + nt * 16) * BK + aCol[h]);
#pragma unroll
        for (int mt = 0; mt < 4; ++mt)
#pragma unroll
          for (int nt = 0; nt < 4; ++nt)
            acc[mt][nt] = __builtin_amdgcn_mfma_f32_16x16x32_bf16(
                af[mt], bf[nt], acc[mt][nt], 0, 0, 0);
      }
      __builtin_amdgcn_s_setprio(0);

      // -- counted wait + barrier
      if (t < 126) {
        asm volatile("s_waitcnt vmcnt(4)" ::: "memory");  // B(t+1)+A(t+1) done
        __builtin_amdgcn_s_barrier();
      } else if (t == 126) {
        asm volatile("s_waitcnt vmcnt(0)" ::: "memory");  // drain for last tile
        __builtin_amdgcn_s_barrier();
      }

      // -- rotate buffers
      u16* ta = aC_; aC_ = aN; aN = ta;
      u16* tb = bC; bC = bN; bN = bS; bS = tb;
    }
  }

  // ---- epilogue: out = acc * g(w[:,7]) + sum_d w[b,d]*biases[d,o]
  float bcol[4][8];
#pragma unroll
  for (int nt = 0; nt < 4; ++nt) {
    const int col = n0 + wc * 64 + nt * 16 + l16;
#pragma unroll
    for (int dd = 0; dd < 8; ++dd) bcol[nt][dd] = biases[dd * OUT_ + col];
  }
#pragma unroll
  for (int mt = 0; mt < 4; ++mt) {
#pragma unroll
    for (int r = 0; r < 4; ++r) {
      const int grow = m0 + wr * 64 + mt * 16 + quad * 4 + r;
      const v4f* wpg = (const v4f*)(w + (size_t)grow * D_);
      const v4f wa = wpg[0], wb = wpg[1];
      const float wlast = wp[mt][r];
#pragma unroll
      for (int nt = 0; nt < 4; ++nt) {
        const int col = n0 + wc * 64 + nt * 16 + l16;
        const float bias = wa[0] * bcol[nt][0] + wa[1] * bcol[nt][1] +
                           wa[2] * bcol[nt][2] + wa[3] * bcol[nt][3] +
                           wb[0] * bcol[nt][4] + wb[1] * bcol[nt][5] +
                           wb[2] * bcol[nt][6] + wb[3] * bcol[nt][7];
        out[(size_t)grow * OUT_ + col] = acc[mt][nt][r] * wlast + bias;
      }
    }
  }
}

extern "C" void kernel_launch(void* const* d_in, const int* in_sizes, int n_in,
                              void* d_out, int out_size, void* d_ws, size_t ws_size,
                              hipStream_t stream) {
  const float* input   = (const float*)d_in[0];
  const float* w       = (const float*)d_in[1];
  const float* weights = (const float*)d_in[2];
  const float* biases  = (const float*)d_in[3];
  float* out = (float*)d_out;

  u16* inBf = (u16*)d_ws;                               // 16 MB
  u16* wtBf = inBf + (size_t)B_ * IN_;                  // 16 MB

  const int totalF4 = (B_ * IN_ + D_ * OUT_ * IN_) / 4;
  convert_both<<<dim3(totalF4 / 256), 256, 0, stream>>>(input, weights, inBf, wtBf);
  gemm_rs<<<dim3(512), 256, 0, stream>>>(inBf, wtBf, w, biases, out);
}